// Round 9
// baseline (106.367 us; speedup 1.0000x reference)
//
#include <hip/hip_runtime.h>

// Chamfer distance, B=16 clouds x N=4096 x D=3, fp32, via bf16-split MFMA.
// S_ij by ONE v_mfma_f32_16x16x32_bf16 (K=32, f32x4 acc):
//   k0-2: xh*-2yh  k3-5: xl*-2yh  k6-8: xh*-2yl  k9-11: xl*-2yl
//   k12,13: x2h,x2l*1  k14,15: 1*y2h,y2l  (k16-31 zero; lanes 32-63 zero ops)
// History: R8 96.0 (2048 blocks, j-sliced: only cd_mfma ever <43us!).
//   R9/R10 atomics+fences 137 REGRESSION. R11 min3 NEUTRAL. R12 lb(256,5)
//   FAILED. R13 fused 100.8. R14 dir-split 1024 blocks: cd_fused 43.2.
//   R15 prep-once+gload_lds: 47. R16 16x16 clean acc: 43.7.
//   KEY EVIDENCE: R14/R15/R16 vary per-entry VALU 3x, MFMA shape, staging,
//   LDS size -> all 43-47us; Occupancy pinned ~27%, VALUBusy ~57%.
//   Work-insensitive => concurrency-starved (too few resident waves), not
//   VALU/MFMA/BW-bound. R8's 2048-block slicing was the one faster config.
// R17: R16 structure + j-slice 4-way. Grid (32x4, 16, 2) = 4096 blocks,
//   1024 pts/block as 4 x 256-pt stages (8KB dbuf + scratch ~ 8.5KB LDS ->
//   8 blocks/CU possible). Slice-partial row-mins -> rowpart (2MB, plain
//   stores), folded with sum by cd_reduce. cd_mfma has no atomic epilogue.
//   Pre-commit: if cd_mfma still ~43us at 4x blocks, the pin is external.

namespace {

constexpr int kB = 16;
constexpr int kN = 4096;
constexpr int kPlane = kB * kN;
constexpr int kJS = 4;                    // j-slices
constexpr int kStage = 256;               // points per LDS stage
constexpr int kNS = (kN / kJS) / kStage;  // 4 stages per slice
constexpr float kScale = 1.0f / (float)(kB * kN);

typedef short bf16x8 __attribute__((ext_vector_type(8)));
typedef float f32x4 __attribute__((ext_vector_type(4)));
typedef unsigned short u16;

__device__ inline u16 bf16_rn(float f) {
  union { float f; unsigned u; } v; v.f = f;
  unsigned r = v.u + 0x7fffu + ((v.u >> 16) & 1u);
  return (u16)(r >> 16);
}
__device__ inline float bf16_f(u16 h) {
  union { unsigned u; float f; } v; v.u = (unsigned)h << 16;
  return v.f;
}
__device__ inline unsigned pk2(u16 lo, u16 hi) {
  return (unsigned)lo | ((unsigned)hi << 16);
}

__global__ void init_out(float* out) { out[0] = 0.0f; }

// One thread per point p: A row (row-major 32B at p*32) and B row
// (plane-separated per 256-pt stage: [cloud][stg][khalf][pl] 16B) for BOTH
// inputs. Zeroes out[0].
// A u16[16]: [xh0..2, xl0..2, xh0..2, xl0..2, x2h, x2l, 1, 1]
// B u16[16]: [-2yh0..2, -2yh0..2, -2yl0..2, -2yl0..2, 1, 1, y2h, y2l]
__global__ __launch_bounds__(256) void cd_prep(
    const float* __restrict__ pred, const float* __restrict__ targ,
    u16* __restrict__ Apred, u16* __restrict__ Atarg,
    u16* __restrict__ Bpred, u16* __restrict__ Btarg,
    float* __restrict__ out) {
  const int p = blockIdx.x * 256 + threadIdx.x;   // 0..kPlane-1
  if (p == 0) out[0] = 0.0f;
  const int cloud = p >> 12, q = p & (kN - 1);
  const int stg = q >> 8, pl = q & (kStage - 1);
  // u16 units: cloud block 65536 (128KB), stage 4096 (8KB), khalf 2048 (4KB)
  const size_t boff = (size_t)cloud * 65536 + (size_t)stg * 4096 + (size_t)pl * 8;
  const u16 one = 0x3F80;

  const float* srcs[2] = {pred, targ};
  u16* adsts[2] = {Apred, Atarg};
  u16* bdsts[2] = {Bpred, Btarg};
#pragma unroll
  for (int which = 0; which < 2; ++which) {
    const float a = srcs[which][3 * p], c = srcs[which][3 * p + 1],
                d = srcs[which][3 * p + 2];
    const u16 ah = bf16_rn(a), ch = bf16_rn(c), dh = bf16_rn(d);
    const u16 al = bf16_rn(a - bf16_f(ah));
    const u16 cl = bf16_rn(c - bf16_f(ch));
    const u16 dl = bf16_rn(d - bf16_f(dh));
    const float s2 = fmaf(a, a, fmaf(c, c, d * d));
    const u16 s2h = bf16_rn(s2);
    const u16 s2l = bf16_rn(s2 - bf16_f(s2h));
    {  // A row
      uint4 w0, w1;
      w0.x = pk2(ah, ch); w0.y = pk2(dh, al); w0.z = pk2(cl, dl); w0.w = pk2(ah, ch);
      w1.x = pk2(dh, al); w1.y = pk2(cl, dl); w1.z = pk2(s2h, s2l); w1.w = pk2(one, one);
      uint4* dst = reinterpret_cast<uint4*>(adsts[which] + (size_t)p * 16);
      dst[0] = w0; dst[1] = w1;
    }
    {  // B row (-2 scale exact in bf16)
      const u16 nah = bf16_rn(-2.0f * bf16_f(ah));
      const u16 nch = bf16_rn(-2.0f * bf16_f(ch));
      const u16 ndh = bf16_rn(-2.0f * bf16_f(dh));
      const u16 nal = bf16_rn(-2.0f * bf16_f(al));
      const u16 ncl = bf16_rn(-2.0f * bf16_f(cl));
      const u16 ndl = bf16_rn(-2.0f * bf16_f(dl));
      uint4 w0, w1;
      w0.x = pk2(nah, nch); w0.y = pk2(ndh, nah); w0.z = pk2(nch, ndh); w0.w = pk2(nal, ncl);
      w1.x = pk2(ndl, nal); w1.y = pk2(ncl, ndl); w1.z = pk2(one, one); w1.w = pk2(s2h, s2l);
      *reinterpret_cast<uint4*>(bdsts[which] + boff) = w0;
      *reinterpret_cast<uint4*>(bdsts[which] + boff + 2048) = w1;
    }
  }
}

// Block = 4 waves x 32 rows = 128 rows of X (cloud, chunk); scans its
// 1024-point j-slice staged through double-buffered LDS (global_load_lds).
// 16x16x32: A row/col = lane&15, k-group = lane>>4 (groups 2,3 zero).
// C/D [m89]: col=lane&15, row=(lane>>4)*4+reg.
// Slice-partial row-mins -> 16-lane butterfly -> rowpart (plain stores).
__global__ __launch_bounds__(256) void cd_mfma(
    const u16* __restrict__ Apred, const u16* __restrict__ Atarg,
    const u16* __restrict__ Bpred, const u16* __restrict__ Btarg,
    float* __restrict__ rowpart) {
  __shared__ uint4 Blds4[1028];   // 16 KB dbuf (2x8KB) + 16B zero scratch

  const int t = threadIdx.x;
  const int w = t >> 6, lane = t & 63;
  const int l15 = lane & 15, kg = lane >> 4;   // k-group 0..3
  const bool act = (kg < 2);                   // lanes 32-63: zero operands
  const int g = kg & 1;                        // k-half for active lanes
  const int bx = blockIdx.x;
  const int chunk = bx & 31;         // 0..31 -> 128 rows per block
  const int slice = bx >> 5;         // 0..kJS-1
  const int cloud = blockIdx.y;      // 0..15
  const int dir = blockIdx.z;        // 0: pred rows vs targ; 1: swapped
  const u16* __restrict__ A = dir ? Atarg : Apred;
  const u16* __restrict__ B = dir ? Bpred : Btarg;

  // ---- A fragments: rows band+l15 (af0) and band+16+l15 (af1) ----
  const int arow0 = cloud * kN + chunk * 128 + w * 32 + l15;
  union { uint4 u; bf16x8 v; } af0, af1;
  af0.u = make_uint4(0, 0, 0, 0);
  af1.u = make_uint4(0, 0, 0, 0);
  if (act) {
    af0.u = *reinterpret_cast<const uint4*>(A + (size_t)arow0 * 16 + g * 8);
    af1.u = *reinterpret_cast<const uint4*>(A + (size_t)(arow0 + 16) * 16 + g * 8);
  }

  // ---- staging: linear copy, 2 x global_load_lds(16B) per thread/stage ----
  // slice base: cloud*128KB + slice*32KB; stage: 8KB
  const char* bsl = (const char*)B + (size_t)cloud * 131072 + (size_t)slice * 32768;
  char* ldsbase = (char*)Blds4;
#define STAGE(st, buf)                                                        \
  {                                                                           \
    const char* _src = bsl + (size_t)(st) * 8192;                             \
    char* _dst = ldsbase + (buf) * 8192;                                      \
    _Pragma("unroll")                                                         \
    for (int i = 0; i < 2; ++i) {                                             \
      __builtin_amdgcn_global_load_lds(                                       \
          (const __attribute__((address_space(1))) void*)(_src +              \
              ((w * 2 + i) * 64 + lane) * 16),                                \
          (__attribute__((address_space(3))) void*)(_dst + (w * 2 + i) * 1024),\
          16, 0, 0);                                                          \
    }                                                                         \
  }

  // B read addressing: active lanes walk their k-half plane; zero lanes
  // broadcast-read the 16B zero scratch (stride 0).
  const int rb0 = act ? (g * 4096 + l15 * 16) : 16384;
  const int rstep = act ? 256 : 0;       // bytes per j-tile (16 pts x 16B)
  const int bufstep = act ? 8192 : 0;

  f32x4 z4;
#pragma unroll
  for (int r = 0; r < 4; ++r) z4[r] = 0.0f;
  float rmin0[4], rmin1[4];
#pragma unroll
  for (int r = 0; r < 4; ++r) { rmin0[r] = 1e30f; rmin1[r] = 1e30f; }

  STAGE(0, 0);
  if (t == 0) Blds4[1024] = make_uint4(0, 0, 0, 0);   // zero scratch
  __syncthreads();   // buf0 + scratch ready

  for (int st = 0; st < kNS; ++st) {
    if (st < kNS - 1) STAGE(st + 1, (st + 1) & 1);
    const char* pb = ldsbase + rb0 + (st & 1) * bufstep;
#pragma unroll 4
    for (int jt = 0; jt < kStage / 16; ++jt) {   // 16 j-tiles of 16 cols
      union { uint4 u; bf16x8 v; } bu;
      bu.u = *reinterpret_cast<const uint4*>(pb);
      pb += rstep;
      const f32x4 s0 =
          __builtin_amdgcn_mfma_f32_16x16x32_bf16(af0.v, bu.v, z4, 0, 0, 0);
      const f32x4 s1 =
          __builtin_amdgcn_mfma_f32_16x16x32_bf16(af1.v, bu.v, z4, 0, 0, 0);
#pragma unroll
      for (int r = 0; r < 4; ++r) {
        rmin0[r] = fminf(rmin0[r], s0[r]);
        rmin1[r] = fminf(rmin1[r], s1[r]);
      }
    }
    __syncthreads();   // stage loads landed; compute done before overwrite
  }
#undef STAGE

  // Butterfly over the 16 lanes of each k-group (different cols, same rows).
#pragma unroll
  for (int sh = 1; sh < 16; sh <<= 1) {
#pragma unroll
    for (int r = 0; r < 4; ++r) {
      rmin0[r] = fminf(rmin0[r], __shfl_xor(rmin0[r], sh, 64));
      rmin1[r] = fminf(rmin1[r], __shfl_xor(rmin1[r], sh, 64));
    }
  }
  // Lane group kg holds rows kg*4+r (af0) and 16+kg*4+r (af1) of the wave's
  // 32-row band. One store lane per group.
  if (l15 == 0) {
    float* rp = rowpart + (((size_t)dir * kJS + slice) * kB + cloud) * kN +
                chunk * 128 + w * 32;
#pragma unroll
    for (int r = 0; r < 4; ++r) {
      rp[kg * 4 + r] = rmin0[r];
      rp[16 + kg * 4 + r] = rmin1[r];
    }
  }
}

// Per (dir, cloud, row): min over kJS slice-partials; block-sum -> atomicAdd.
__global__ __launch_bounds__(256) void cd_reduce(
    const float* __restrict__ rowpart, float* __restrict__ out) {
  const int u = blockIdx.x * 256 + threadIdx.x;   // 0..2*kPlane-1
  const int dir = u >> 16, rest = u & 65535;
  const int cloud = rest >> 12, row = rest & (kN - 1);
  float rm = 1e30f;
#pragma unroll
  for (int s2 = 0; s2 < kJS; ++s2)
    rm = fminf(rm, rowpart[(((size_t)dir * kJS + s2) * kB + cloud) * kN + row]);
  float s = rm;
  for (int o = 32; o > 0; o >>= 1) s += __shfl_down(s, o, 64);
  __shared__ float wsum[4];
  const int lane = threadIdx.x & 63, wv = threadIdx.x >> 6;
  if (lane == 0) wsum[wv] = s;
  __syncthreads();
  if (threadIdx.x == 0)
    atomicAdd(out, (wsum[0] + wsum[1] + wsum[2] + wsum[3]) * kScale);
}

// ---------- fallback (small ws): R5-style pk_fma direct kernel ----------
template <int KX>
__global__ __launch_bounds__(256) void chamfer_direct(
    const float* __restrict__ pred, const float* __restrict__ targ,
    float* __restrict__ out) {
  __shared__ float4 tA[128], tB[128];
  const int t = threadIdx.x;
  const int xb = blockIdx.x, b = blockIdx.y, dir = blockIdx.z;
  const float* __restrict__ X = dir ? targ : pred;
  const float* __restrict__ Y = dir ? pred : targ;
  float2 xx2[KX], xy2[KX], xz2[KX];
  float x2[KX], mn[KX];
  const int ibase = b * kN + xb * (256 * KX) + t;
#pragma unroll
  for (int k = 0; k < KX; ++k) {
    const int i = ibase + k * 256;
    const float a = X[3 * i], c = X[3 * i + 1], d = X[3 * i + 2];
    x2[k] = fmaf(a, a, fmaf(c, c, d * d));
    xx2[k] = make_float2(-2.0f * a, -2.0f * a);
    xy2[k] = make_float2(-2.0f * c, -2.0f * c);
    xz2[k] = make_float2(-2.0f * d, -2.0f * d);
    mn[k] = 1e30f;
  }
  for (int t0 = 0; t0 < kN; t0 += 256) {
    __syncthreads();
    if (t < 128) {
      const int j0 = 3 * (b * kN + t0 + 2 * t);
      const float a0 = Y[j0], c0 = Y[j0 + 1], d0 = Y[j0 + 2];
      const float a1 = Y[j0 + 3], c1 = Y[j0 + 4], d1 = Y[j0 + 5];
      tA[t] = make_float4(a0, a1, c0, c1);
      tB[t] = make_float4(d0, d1, fmaf(a0, a0, fmaf(c0, c0, d0 * d0)),
                          fmaf(a1, a1, fmaf(c1, c1, d1 * d1)));
    }
    __syncthreads();
    for (int jj = 0; jj < 128; ++jj) {
      const float4 qa = tA[jj], qb = tB[jj];
      const float2 qx = make_float2(qa.x, qa.y), qy = make_float2(qa.z, qa.w);
      const float2 qz = make_float2(qb.x, qb.y), qw = make_float2(qb.z, qb.w);
#pragma unroll
      for (int k = 0; k < KX; ++k) {
        float2 acc;
        asm("v_pk_fma_f32 %0, %1, %2, %3\n\t"
            "v_pk_fma_f32 %0, %4, %5, %0\n\t"
            "v_pk_fma_f32 %0, %6, %7, %0"
            : "=&v"(acc)
            : "v"(xz2[k]), "v"(qz), "v"(qw), "v"(xy2[k]), "v"(qy),
              "v"(xx2[k]), "v"(qx));
        asm("v_min3_f32 %0, %0, %1, %2" : "+v"(mn[k]) : "v"(acc.x), "v"(acc.y));
      }
    }
  }
  float s = 0.0f;
#pragma unroll
  for (int k = 0; k < KX; ++k) s += x2[k] + mn[k];
  for (int o = 32; o > 0; o >>= 1) s += __shfl_down(s, o, 64);
  __shared__ float wsum[4];
  const int lane = t & 63, wv = t >> 6;
  if (lane == 0) wsum[wv] = s;
  __syncthreads();
  if (t == 0)
    atomicAdd(out, (wsum[0] + wsum[1] + wsum[2] + wsum[3]) * kScale);
}

}  // namespace

extern "C" void kernel_launch(void* const* d_in, const int* in_sizes, int n_in,
                              void* d_out, int out_size, void* d_ws,
                              size_t ws_size, hipStream_t stream) {
  const float* pred = (const float*)d_in[0];
  const float* targ = (const float*)d_in[1];
  float* out = (float*)d_out;

  const size_t needOne = (size_t)kPlane * 16 * sizeof(u16);       // 2 MB each
  const size_t needRow = (size_t)2 * kJS * kPlane * sizeof(float) / kB * kB;
  const size_t needRowB = (size_t)2 * kJS * kB * kN * sizeof(float);  // 2 MB
  (void)needRow;
  if (ws_size >= 4 * needOne + needRowB) {                        // 10 MB
    u16* Apred = (u16*)d_ws;
    u16* Atarg = (u16*)((char*)d_ws + needOne);
    u16* Bpred = (u16*)((char*)d_ws + 2 * needOne);
    u16* Btarg = (u16*)((char*)d_ws + 3 * needOne);
    float* rowpart = (float*)((char*)d_ws + 4 * needOne);
    cd_prep<<<dim3(kPlane / 256), 256, 0, stream>>>(pred, targ, Apred, Atarg,
                                                    Bpred, Btarg, out);
    cd_mfma<<<dim3(32 * kJS, kB, 2), 256, 0, stream>>>(Apred, Atarg, Bpred,
                                                       Btarg, rowpart);
    cd_reduce<<<dim3(2 * kPlane / 256), 256, 0, stream>>>(rowpart, out);
  } else {
    init_out<<<dim3(1), dim3(1), 0, stream>>>(out);
    constexpr int KX = 8;
    dim3 grid(kN / (256 * KX), kB, 2);
    chamfer_direct<KX><<<grid, 256, 0, stream>>>(pred, targ, out);
  }
}